// Round 3
// baseline (1384.579 us; speedup 1.0000x reference)
//
#include <hip/hip_runtime.h>
#include <hip/hip_bf16.h>
#include <stdint.h>

typedef __bf16 v8bf __attribute__((ext_vector_type(8)));
typedef float  v4f  __attribute__((ext_vector_type(4)));
typedef unsigned short u16;
typedef unsigned int   u32;

#define B_ROWS   8192
#define N_SUP    100000
#define N_CLS    1000
#define CPAD     1024
#define DIM      768
#define MSUP_PAD 100352   // 784 * 128

// ---------- helpers ----------
__device__ __forceinline__ u16 f2bf(float f) {           // native RNE cvt
    __bf16 b = (__bf16)f;
    union { __bf16 b; u16 u; } v; v.b = b; return v.u;
}
__device__ __forceinline__ float bf2f(u16 b) {
    union { u32 u; float f; } v; v.u = ((u32)b) << 16; return v.f;
}
// async global->LDS, 16B per lane; LDS dst = wave-uniform base + lane*16
__device__ __forceinline__ void glds16(const void* g, void* l) {
    __builtin_amdgcn_global_load_lds((const __attribute__((address_space(1))) u32*)g,
                                     (__attribute__((address_space(3))) u32*)l, 16, 0, 0);
}

__device__ __forceinline__ float block_sum(float v, float* red) {
    #pragma unroll
    for (int o = 32; o > 0; o >>= 1) v += __shfl_down(v, o);
    int wv = threadIdx.x >> 6, ln = threadIdx.x & 63;
    if (ln == 0) red[wv] = v;
    __syncthreads();
    return red[0] + red[1] + red[2] + red[3];
}
__device__ __forceinline__ float block_max(float v, float* red) {
    #pragma unroll
    for (int o = 32; o > 0; o >>= 1) v = fmaxf(v, __shfl_down(v, o));
    int wv = threadIdx.x >> 6, ln = threadIdx.x & 63;
    if (ln == 0) red[wv] = v;
    __syncthreads();
    return fmaxf(fmaxf(red[0], red[1]), fmaxf(red[2], red[3]));
}

// XCD chunked bijective swizzle (requires nwg % 8 == 0; true for all grids here)
__device__ __forceinline__ int xcd_swizzle(void) {
    const int nwg = gridDim.x * gridDim.y;
    const int bid = blockIdx.y * gridDim.x + blockIdx.x;
    const int q = nwg >> 3;
    return (bid & 7) * q + (bid >> 3);
}

// ---------- fp32 -> bf16 conversion (W only) ----------
__global__ __launch_bounds__(256)
void conv_pad_kernel(const float* __restrict__ in, u16* __restrict__ out,
                     int n_real) {
    #pragma unroll
    for (int s = 0; s < 3; s++) {
        size_t f4 = (size_t)blockIdx.x * 768 + s * 256 + threadIdx.x;
        int row = (int)(f4 / 192);
        size_t eb = f4 * 4;
        ushort4 o;
        if (row < n_real) {
            float4 v = *(const float4*)(in + eb);
            o.x = f2bf(v.x); o.y = f2bf(v.y); o.z = f2bf(v.z); o.w = f2bf(v.w);
        } else {
            o.x = 0; o.y = 0; o.z = 0; o.w = 0;
        }
        *(ushort4*)(out + eb) = o;
    }
}

// ---------- per-class queue build (one pass over labels) ----------
__global__ __launch_bounds__(256)
void build_queues_kernel(const int* __restrict__ labels, int* __restrict__ qcnt,
                         int* __restrict__ qlist) {
    int i = blockIdx.x * 256 + threadIdx.x;
    if (i < N_SUP) {
        int l = labels[i];
        int p = atomicAdd(&qcnt[l], 1);
        if (p < 256) qlist[l * 256 + p] = i;
    }
}

// ---------- fused adapter GEMM: A fp32 [M,768]; h = A @ W^T + b ----------
// A-fragments loaded DIRECTLY global->reg (fp32, prefetched one K-step ahead,
// cvt to bf16 in-reg after the barrier drain guarantees arrival).
// W via glds16 -> LDS (L2-resident), double-buffered, XOR-swizzled (conflict-free).
// grid = (6, M/128), block = 256 (4 waves, 2x2), XCD swizzle.
__global__ __launch_bounds__(256, 2)
void adapter_gemm_kernel(const float* __restrict__ A, const u16* __restrict__ Wb,
                         const float* __restrict__ bias, int n_real,
                         u16* __restrict__ val, float* __restrict__ ss) {
    __shared__ u16 Bs[2][128 * 64];

    const int tid  = threadIdx.x;
    const int wave = tid >> 6, lane = tid & 63;
    const int fq = lane >> 4, fr = lane & 15;

    const int swz = xcd_swizzle();
    const int blk_m = (swz / gridDim.x) * 128;
    const int blk_n = (swz % gridDim.x) * 128;

    const int wm = (wave & 1) * 64, wn = (wave >> 1) * 64;

    v4f acc[4][4];
    #pragma unroll
    for (int i = 0; i < 4; i++)
        #pragma unroll
        for (int j = 0; j < 4; j++) acc[i][j] = (v4f){0.f, 0.f, 0.f, 0.f};

    // W stage: linear LDS dest, pre-swizzled global granule (LDS[r][g]=glob[r][g^(r&7)])
    const int rb  = lane >> 3;
    const int cbs = ((lane & 7) ^ rb) * 8;
    const u16* gB = Wb + (size_t)(blk_n + wave * 8 + rb) * DIM + cbs;

    auto STAGEB = [&](int buf, int k0) {
        #pragma unroll
        for (int p = 0; p < 4; p++)
            glds16(gB + (size_t)p * 32 * DIM + k0, &Bs[buf][p * 2048 + wave * 512]);
    };

    // A fragment base pointers: frag f = ks*4+i -> row blk_m+wm+i*16+fr, col k0+ks*32+fq*8
    const float* gA[4];
    bool rowok[4];
    #pragma unroll
    for (int i = 0; i < 4; i++) {
        int row = blk_m + wm + i * 16 + fr;
        rowok[i] = row < n_real;
        gA[i] = A + (size_t)row * DIM + fq * 8;
    }

    float4 pa[8][2];   // prefetched fp32 A-fragments for the NEXT K-step
    v8bf   af[8];      // bf16 A-fragments for the CURRENT K-step

    auto LOADPA = [&](int k0) {
        #pragma unroll
        for (int ks = 0; ks < 2; ks++)
            #pragma unroll
            for (int i = 0; i < 4; i++) {
                const float* p = gA[i] + k0 + ks * 32;
                if (rowok[i]) {
                    pa[ks * 4 + i][0] = *(const float4*)(p);
                    pa[ks * 4 + i][1] = *(const float4*)(p + 4);
                } else {
                    pa[ks * 4 + i][0] = make_float4(0.f, 0.f, 0.f, 0.f);
                    pa[ks * 4 + i][1] = make_float4(0.f, 0.f, 0.f, 0.f);
                }
            }
    };
    auto CVT = [&]() {
        #pragma unroll
        for (int f = 0; f < 8; f++) {
            af[f][0] = (__bf16)pa[f][0].x; af[f][1] = (__bf16)pa[f][0].y;
            af[f][2] = (__bf16)pa[f][0].z; af[f][3] = (__bf16)pa[f][0].w;
            af[f][4] = (__bf16)pa[f][1].x; af[f][5] = (__bf16)pa[f][1].y;
            af[f][6] = (__bf16)pa[f][1].z; af[f][7] = (__bf16)pa[f][1].w;
        }
    };
    auto COMPUTE = [&](int buf) {
        #pragma unroll
        for (int ks = 0; ks < 2; ks++) {
            const int gbase = ks * 4;
            v8bf bfr[4];
            #pragma unroll
            for (int j = 0; j < 4; j++) {
                int rowb = wn + j * 16 + fr;
                int g    = (gbase + fq) ^ (fr & 7);
                bfr[j] = *(const v8bf*)(&Bs[buf][rowb * 64 + g * 8]);
            }
            __builtin_amdgcn_s_setprio(1);
            #pragma unroll
            for (int i = 0; i < 4; i++)
                #pragma unroll
                for (int j = 0; j < 4; j++)
                    acc[i][j] = __builtin_amdgcn_mfma_f32_16x16x32_bf16(
                        af[ks * 4 + i], bfr[j], acc[i][j], 0, 0, 0);
            __builtin_amdgcn_s_setprio(0);
        }
    };

    // prologue: A(k0=0) in flight, W(k0=0) staged
    LOADPA(0);
    STAGEB(0, 0);
    __syncthreads();           // drain: pa(0) + Bs[0] ready
    int buf = 0;

    #define ASTEP(K0)                                                  \
        CVT();                 /* consume pa (ready: last drain) */    \
        LOADPA(K0);            /* issue next-step A loads */           \
        STAGEB(buf ^ 1, K0);   /* issue next-step W glds */            \
        COMPUTE(buf);          /* MFMA hides both */                   \
        __syncthreads();       /* drain -> next step ready */          \
        buf ^= 1;

    ASTEP(64)  ASTEP(128) ASTEP(192) ASTEP(256) ASTEP(320) ASTEP(384)
    ASTEP(448) ASTEP(512) ASTEP(576) ASTEP(640) ASTEP(704)
    #undef ASTEP
    CVT();
    COMPUTE(buf);              // last K-step

    // epilogue: val = silu(h) + t (t fp32 from A, L2-hot); bf16 store; row ss
    #pragma unroll
    for (int i = 0; i < 4; i++) {
        int r0 = blk_m + wm + i * 16 + fq * 4;
        float ssp[4] = {0.f, 0.f, 0.f, 0.f};
        #pragma unroll
        for (int j = 0; j < 4; j++) {
            int col = blk_n + wn + j * 16 + fr;
            float bv = bias[col];
            #pragma unroll
            for (int r2 = 0; r2 < 4; r2++) {
                int gr = r0 + r2;
                float h = acc[i][j][r2] + bv;
                float t = (gr < n_real) ? A[(size_t)gr * DIM + col] : 0.f;
                float v = h / (1.f + __expf(-h)) + t;
                ssp[r2] += v * v;
                val[(size_t)gr * DIM + col] = f2bf(v);
            }
        }
        #pragma unroll
        for (int r2 = 0; r2 < 4; r2++) {
            float s = ssp[r2];
            s += __shfl_xor(s, 1); s += __shfl_xor(s, 2);
            s += __shfl_xor(s, 4); s += __shfl_xor(s, 8);
            if (fr == 0) atomicAdd(&ss[r0 + r2], s);
        }
    }
}

// ---------- x normalize: emb = val / max(||val||, eps); fp32 + bf16 out ----------
__global__ void norm_x_kernel(const u16* __restrict__ val, const float* __restrict__ ss,
                              float* __restrict__ emb, u16* __restrict__ emb_bf) {
    int row = blockIdx.x;
    float sc = 1.f / fmaxf(sqrtf(ss[row]), 1e-12f);
    size_t b = (size_t)row * DIM + threadIdx.x * 4;
    ushort4 v = *(const ushort4*)(val + b);
    float4 o;
    o.x = bf2f(v.x) * sc; o.y = bf2f(v.y) * sc;
    o.z = bf2f(v.z) * sc; o.w = bf2f(v.w) * sc;
    *(float4*)(emb + b) = o;
    ushort4 ob; ob.x = f2bf(o.x); ob.y = f2bf(o.y); ob.z = f2bf(o.z); ob.w = f2bf(o.w);
    *(ushort4*)(emb_bf + b) = ob;
}

// ---------- prototypes: one class per block; prebuilt queue, 4-way ILP gather ----------
__global__ __launch_bounds__(256)
void proto_kernel(const u16* __restrict__ val_bf, const float* __restrict__ ss,
                  const int* __restrict__ qcnt, const int* __restrict__ qlist,
                  u16* __restrict__ proto_bf) {
    __shared__ float red[4];
    const int cls = blockIdx.x, tid = threadIdx.x;
    int n = qcnt[cls]; if (n > 256) n = 256;
    const int* ql = qlist + (size_t)cls * 256;
    float a0 = 0.f, a1 = 0.f, a2 = 0.f;
    int e = 0;
    for (; e + 4 <= n; e += 4) {
        int r0 = ql[e], r1 = ql[e + 1], r2 = ql[e + 2], r3 = ql[e + 3];
        float s0 = 1.f / fmaxf(sqrtf(ss[r0]), 1e-12f);
        float s1 = 1.f / fmaxf(sqrtf(ss[r1]), 1e-12f);
        float s2 = 1.f / fmaxf(sqrtf(ss[r2]), 1e-12f);
        float s3 = 1.f / fmaxf(sqrtf(ss[r3]), 1e-12f);
        const u16* p0 = val_bf + (size_t)r0 * DIM;
        const u16* p1 = val_bf + (size_t)r1 * DIM;
        const u16* p2 = val_bf + (size_t)r2 * DIM;
        const u16* p3 = val_bf + (size_t)r3 * DIM;
        u16 x00 = p0[tid], x01 = p0[tid + 256], x02 = p0[tid + 512];
        u16 x10 = p1[tid], x11 = p1[tid + 256], x12 = p1[tid + 512];
        u16 x20 = p2[tid], x21 = p2[tid + 256], x22 = p2[tid + 512];
        u16 x30 = p3[tid], x31 = p3[tid + 256], x32 = p3[tid + 512];
        a0 += bf2f(x00) * s0 + bf2f(x10) * s1 + bf2f(x20) * s2 + bf2f(x30) * s3;
        a1 += bf2f(x01) * s0 + bf2f(x11) * s1 + bf2f(x21) * s2 + bf2f(x31) * s3;
        a2 += bf2f(x02) * s0 + bf2f(x12) * s1 + bf2f(x22) * s2 + bf2f(x32) * s3;
    }
    for (; e < n; e++) {
        int row = ql[e];
        float sc = 1.f / fmaxf(sqrtf(ss[row]), 1e-12f);
        const u16* vr = val_bf + (size_t)row * DIM;
        a0 += bf2f(vr[tid])       * sc;
        a1 += bf2f(vr[tid + 256]) * sc;
        a2 += bf2f(vr[tid + 512]) * sc;
    }
    float inv_cnt = 1.f / fmaxf((float)n, 1.f);
    float m0 = a0 * inv_cnt, m1 = a1 * inv_cnt, m2 = a2 * inv_cnt;
    float tot = block_sum(m0 * m0 + m1 * m1 + m2 * m2, red);
    float sc2 = (n > 0) ? 1.f / fmaxf(sqrtf(tot), 1e-12f) : 0.f;
    size_t b = (size_t)cls * DIM;
    proto_bf[b + tid]       = f2bf(m0 * sc2);
    proto_bf[b + tid + 256] = f2bf(m1 * sc2);
    proto_bf[b + tid + 512] = f2bf(m2 * sc2);
}

// ---------- cos GEMM: A (emb_bf) direct global->reg, B (proto) glds16+swizzle ----------
// grid = (CPAD/128, B_ROWS/128); fused exp -> logits
__global__ __launch_bounds__(256, 2)
void cos_gemm_kernel(const u16* __restrict__ Ab, const u16* __restrict__ Pb,
                     float* __restrict__ logits) {
    __shared__ u16 Bs[2][128 * 64];
    const int tid  = threadIdx.x;
    const int wave = tid >> 6, lane = tid & 63;
    const int fq = lane >> 4, fr = lane & 15;

    const int swz = xcd_swizzle();
    const int blk_m = (swz / gridDim.x) * 128;
    const int blk_n = (swz % gridDim.x) * 128;

    const int wm = (wave & 1) * 64, wn = (wave >> 1) * 64;

    v4f acc[4][4];
    #pragma unroll
    for (int i = 0; i < 4; i++)
        #pragma unroll
        for (int j = 0; j < 4; j++) acc[i][j] = (v4f){0.f, 0.f, 0.f, 0.f};

    const int rb  = lane >> 3;
    const int cbs = ((lane & 7) ^ rb) * 8;
    const u16* gB = Pb + (size_t)(blk_n + wave * 8 + rb) * DIM + cbs;

    auto STAGEB = [&](int buf, int k0) {
        #pragma unroll
        for (int p = 0; p < 4; p++)
            glds16(gB + (size_t)p * 32 * DIM + k0, &Bs[buf][p * 2048 + wave * 512]);
    };

    const u16* gA[4];
    #pragma unroll
    for (int i = 0; i < 4; i++)
        gA[i] = Ab + (size_t)(blk_m + wm + i * 16 + fr) * DIM + fq * 8;

    v8bf afA[8], afB[8];
    auto LOADA = [&](v8bf* af, int k0) {
        #pragma unroll
        for (int ks = 0; ks < 2; ks++)
            #pragma unroll
            for (int i = 0; i < 4; i++)
                af[ks * 4 + i] = *(const v8bf*)(gA[i] + k0 + ks * 32);
    };
    auto COMPUTE = [&](int buf, const v8bf* af) {
        #pragma unroll
        for (int ks = 0; ks < 2; ks++) {
            const int gbase = ks * 4;
            v8bf bfr[4];
            #pragma unroll
            for (int j = 0; j < 4; j++) {
                int rowb = wn + j * 16 + fr;
                int g    = (gbase + fq) ^ (fr & 7);
                bfr[j] = *(const v8bf*)(&Bs[buf][rowb * 64 + g * 8]);
            }
            __builtin_amdgcn_s_setprio(1);
            #pragma unroll
            for (int i = 0; i < 4; i++)
                #pragma unroll
                for (int j = 0; j < 4; j++)
                    acc[i][j] = __builtin_amdgcn_mfma_f32_16x16x32_bf16(
                        af[ks * 4 + i], bfr[j], acc[i][j], 0, 0, 0);
            __builtin_amdgcn_s_setprio(0);
        }
    };

    LOADA(afA, 0);
    STAGEB(0, 0);
    __syncthreads();
    int buf = 0;

    #define CSTEP(AFN, AFC, K0)                                        \
        LOADA(AFN, K0); STAGEB(buf ^ 1, K0); COMPUTE(buf, AFC);        \
        __syncthreads(); buf ^= 1;

    CSTEP(afB, afA, 64)  CSTEP(afA, afB, 128) CSTEP(afB, afA, 192)
    CSTEP(afA, afB, 256) CSTEP(afB, afA, 320) CSTEP(afA, afB, 384)
    CSTEP(afB, afA, 448) CSTEP(afA, afB, 512) CSTEP(afB, afA, 576)
    CSTEP(afA, afB, 640) CSTEP(afB, afA, 704)
    #undef CSTEP
    COMPUTE(buf, afB);

    #pragma unroll
    for (int i = 0; i < 4; i++) {
        int r0 = blk_m + wm + i * 16 + fq * 4;
        #pragma unroll
        for (int j = 0; j < 4; j++) {
            int col = blk_n + wn + j * 16 + fr;
            if (col < N_CLS) {
                #pragma unroll
                for (int r2 = 0; r2 < 4; r2++) {
                    float c = acc[i][j][r2];
                    logits[(size_t)(r0 + r2) * N_CLS + col] =
                        __expf(32.0f * (c - 1.0f)) * (1.0f / 0.11f);
                }
            }
        }
    }
}

// ---------- softmax over logits rows ----------
__global__ __launch_bounds__(256)
void softmax_kernel(const float* __restrict__ logits, float* __restrict__ predicts) {
    __shared__ float redm[4];
    __shared__ float reds[4];
    int row = blockIdx.x, tid = threadIdx.x;
    const float* lr = logits + (size_t)row * N_CLS;
    float4 lg = make_float4(-1.f, -1.f, -1.f, -1.f);
    bool act = tid < N_CLS / 4;   // 250
    if (act) lg = *(const float4*)(lr + tid * 4);
    float mx = fmaxf(fmaxf(lg.x, lg.y), fmaxf(lg.z, lg.w));  // logits >= 0
    float mxt = block_max(mx, redm);
    float4 e = make_float4(0.f, 0.f, 0.f, 0.f);
    float s = 0.f;
    if (act) {
        e.x = __expf(lg.x - mxt); e.y = __expf(lg.y - mxt);
        e.z = __expf(lg.z - mxt); e.w = __expf(lg.w - mxt);
        s = e.x + e.y + e.z + e.w;
    }
    float st = block_sum(s, reds);
    float inv = 1.f / st;
    if (act) {
        float4 o; o.x = e.x * inv; o.y = e.y * inv; o.z = e.z * inv; o.w = e.w * inv;
        *(float4*)(predicts + (size_t)row * N_CLS + tid * 4) = o;
    }
}

// ---------- launch ----------
extern "C" void kernel_launch(void* const* d_in, const int* in_sizes, int n_in,
                              void* d_out, int out_size, void* d_ws, size_t ws_size,
                              hipStream_t stream) {
    const float* x      = (const float*)d_in[0];
    const float* sup    = (const float*)d_in[1];
    const int*   labels = (const int*)d_in[2];
    const float* W      = (const float*)d_in[3];
    const float* bias   = (const float*)d_in[4];

    float* predicts = (float*)d_out;
    float* logits   = predicts + (size_t)B_ROWS * N_CLS;
    float* emb      = logits + (size_t)B_ROWS * N_CLS;   // 8192x768 fp32

    char* ws = (char*)d_ws;
    size_t off = 0;
    u16*   w_bf     = (u16*)(ws + off);   off += (size_t)DIM * DIM * 2;
    u16*   val_x    = (u16*)(ws + off);   off += (size_t)B_ROWS * DIM * 2;
    u16*   val_sup  = (u16*)(ws + off);   off += (size_t)MSUP_PAD * DIM * 2;
    u16*   emb_bf   = (u16*)(ws + off);   off += (size_t)B_ROWS * DIM * 2;
    u16*   proto_bf = (u16*)(ws + off);   off += (size_t)CPAD * DIM * 2;
    float* ss_sup   = (float*)(ws + off); off += (size_t)MSUP_PAD * 4;
    float* ss_x     = (float*)(ws + off); off += (size_t)B_ROWS * 4;
    int*   qcnt     = (int*)(ws + off);   off += (size_t)CPAD * 4;
    int*   qlist    = (int*)(ws + off);   off += (size_t)N_CLS * 256 * 4;

    // zero ss_sup, ss_x, qcnt in one shot (contiguous)
    hipMemsetAsync(ss_sup, 0, ((size_t)MSUP_PAD + B_ROWS + CPAD) * 4, stream);

    // W -> bf16 (tiny); per-class queues
    conv_pad_kernel<<<DIM / 4, 256, 0, stream>>>(W, w_bf, DIM);
    build_queues_kernel<<<(N_SUP + 255) / 256, 256, 0, stream>>>(labels, qcnt, qlist);

    // fused adapter GEMMs (fp32 A direct; val bf16 + per-row ss)
    adapter_gemm_kernel<<<dim3(DIM / 128, B_ROWS / 128), 256, 0, stream>>>(
        x, w_bf, bias, B_ROWS, val_x, ss_x);
    adapter_gemm_kernel<<<dim3(DIM / 128, MSUP_PAD / 128), 256, 0, stream>>>(
        sup, w_bf, bias, N_SUP, val_sup, ss_sup);

    // x normalize -> emb (fp32, d_out) + emb_bf
    norm_x_kernel<<<B_ROWS, 192, 0, stream>>>(val_x, ss_x, emb, emb_bf);

    // prototypes (classes >= N_CLS: qcnt==0 -> zeros)
    proto_kernel<<<CPAD, 256, 0, stream>>>(val_sup, ss_sup, qcnt, qlist, proto_bf);

    // cos + exp -> logits (d_out), then softmax -> predicts (d_out)
    cos_gemm_kernel<<<dim3(CPAD / 128, B_ROWS / 128), 256, 0, stream>>>(
        emb_bf, proto_bf, logits);
    softmax_kernel<<<B_ROWS, 256, 0, stream>>>(logits, predicts);
}

// Round 4
// 833.225 us; speedup vs baseline: 1.6617x; 1.6617x over previous
//
#include <hip/hip_runtime.h>
#include <hip/hip_bf16.h>
#include <stdint.h>

typedef __bf16 v8bf __attribute__((ext_vector_type(8)));
typedef float  v4f  __attribute__((ext_vector_type(4)));
typedef unsigned short u16;
typedef unsigned int   u32;

#define B_ROWS   8192
#define N_SUP    100000
#define N_CLS    1000
#define CPAD     1024
#define DIM      768
#define MSUP_PAD 100352   // 784 * 128

// ---------- helpers ----------
__device__ __forceinline__ u16 f2bf(float f) {           // native RNE cvt
    __bf16 b = (__bf16)f;
    union { __bf16 b; u16 u; } v; v.b = b; return v.u;
}
__device__ __forceinline__ float bf2f(u16 b) {
    union { u32 u; float f; } v; v.u = ((u32)b) << 16; return v.f;
}
// async global->LDS, 16B per lane; LDS dst = wave-uniform base + lane*16
__device__ __forceinline__ void glds16(const void* g, void* l) {
    __builtin_amdgcn_global_load_lds((const __attribute__((address_space(1))) u32*)g,
                                     (__attribute__((address_space(3))) u32*)l, 16, 0, 0);
}

#define WAITVM(N) asm volatile("s_waitcnt vmcnt(" #N ")" ::: "memory")
#define CFENCE()  asm volatile("" ::: "memory")

__device__ __forceinline__ float block_sum(float v, float* red) {
    #pragma unroll
    for (int o = 32; o > 0; o >>= 1) v += __shfl_down(v, o);
    int wv = threadIdx.x >> 6, ln = threadIdx.x & 63;
    if (ln == 0) red[wv] = v;
    __syncthreads();
    return red[0] + red[1] + red[2] + red[3];
}
__device__ __forceinline__ float block_max(float v, float* red) {
    #pragma unroll
    for (int o = 32; o > 0; o >>= 1) v = fmaxf(v, __shfl_down(v, o));
    int wv = threadIdx.x >> 6, ln = threadIdx.x & 63;
    if (ln == 0) red[wv] = v;
    __syncthreads();
    return fmaxf(fmaxf(red[0], red[1]), fmaxf(red[2], red[3]));
}

// XCD chunked bijective swizzle (requires nwg % 8 == 0; true for all grids here)
__device__ __forceinline__ int xcd_swizzle(void) {
    const int nwg = gridDim.x * gridDim.y;
    const int bid = blockIdx.y * gridDim.x + blockIdx.x;
    const int q = nwg >> 3;
    return (bid & 7) * q + (bid >> 3);
}

// ---------- fp32 -> bf16 conversion, zero-pad rows >= n_real ----------
// one block per 4 rows, 256 thr, 3 float4 per thr
__global__ __launch_bounds__(256)
void conv_pad_kernel(const float* __restrict__ in, u16* __restrict__ out,
                     int n_real) {
    #pragma unroll
    for (int s = 0; s < 3; s++) {
        size_t f4 = (size_t)blockIdx.x * 768 + s * 256 + threadIdx.x;
        int row = (int)(f4 / 192);            // 192 float4 per row
        size_t eb = f4 * 4;
        ushort4 o;
        if (row < n_real) {
            float4 v = *(const float4*)(in + eb);
            o.x = f2bf(v.x); o.y = f2bf(v.y); o.z = f2bf(v.z); o.w = f2bf(v.w);
        } else {
            o.x = 0; o.y = 0; o.z = 0; o.w = 0;
        }
        *(ushort4*)(out + eb) = o;
    }
}

// ---------- per-class queue build (one pass over labels) ----------
__global__ __launch_bounds__(256)
void build_queues_kernel(const int* __restrict__ labels, int* __restrict__ qcnt,
                         int* __restrict__ qlist) {
    int i = blockIdx.x * 256 + threadIdx.x;
    if (i < N_SUP) {
        int l = labels[i];
        int p = atomicAdd(&qcnt[l], 1);
        if (p < 256) qlist[l * 256 + p] = i;
    }
}

// ---------- adapter GEMM: A bf16 [M,768]; h = A @ W^T + b ----------
// glds16 staging both operands (pre-swizzled source granules, conflict-free reads),
// dbuf + COUNTED vmcnt(8): prefetch for tile t+1 stays in flight across barriers.
// grid = (6, M/128), block = 256 (4 waves 2x2), XCD swizzle. 2 blocks/CU (64KB LDS).
__global__ __launch_bounds__(256, 2)
void adapter_gemm_kernel(const u16* __restrict__ A, const u16* __restrict__ Wb,
                         const float* __restrict__ bias,
                         u16* __restrict__ val, float* __restrict__ ss) {
    __shared__ u16 As[2][128 * 64];
    __shared__ u16 Bs[2][128 * 64];

    const int tid  = threadIdx.x;
    const int wave = tid >> 6, lane = tid & 63;
    const int fq = lane >> 4, fr = lane & 15;

    const int swz = xcd_swizzle();
    const int blk_m = (swz / gridDim.x) * 128;
    const int blk_n = (swz % gridDim.x) * 128;

    const int wm = (wave & 1) * 64, wn = (wave >> 1) * 64;

    v4f acc[4][4];
    #pragma unroll
    for (int i = 0; i < 4; i++)
        #pragma unroll
        for (int j = 0; j < 4; j++) acc[i][j] = (v4f){0.f, 0.f, 0.f, 0.f};

    // staging: LDS[row][g] = global[row][g ^ (row&7)]  (pre-swizzled source granule)
    const int rb  = lane >> 3;
    const int cbs = ((lane & 7) ^ rb) * 8;
    const u16* gA = A  + (size_t)(blk_m + wave * 8 + rb) * DIM + cbs;
    const u16* gB = Wb + (size_t)(blk_n + wave * 8 + rb) * DIM + cbs;

    auto STAGE = [&](int buf, int k0) {   // 8 vmem ops per wave
        #pragma unroll
        for (int p = 0; p < 4; p++) {
            glds16(gA + (size_t)p * 32 * DIM + k0, &As[buf][p * 2048 + wave * 512]);
            glds16(gB + (size_t)p * 32 * DIM + k0, &Bs[buf][p * 2048 + wave * 512]);
        }
    };
    auto COMPUTE = [&](int buf) {
        #pragma unroll
        for (int ks = 0; ks < 2; ks++) {
            const int gbase = ks * 4;
            v8bf af[4], bfr[4];
            #pragma unroll
            for (int i = 0; i < 4; i++) {
                int rowa = wm + i * 16 + fr;      // rowa&7 == fr&7
                int rowb = wn + i * 16 + fr;
                int g    = (gbase + fq) ^ (fr & 7);
                af[i]  = *(const v8bf*)(&As[buf][rowa * 64 + g * 8]);
                bfr[i] = *(const v8bf*)(&Bs[buf][rowb * 64 + g * 8]);
            }
            __builtin_amdgcn_s_setprio(1);
            #pragma unroll
            for (int i = 0; i < 4; i++)
                #pragma unroll
                for (int j = 0; j < 4; j++)
                    acc[i][j] = __builtin_amdgcn_mfma_f32_16x16x32_bf16(
                        af[i], bfr[j], acc[i][j], 0, 0, 0);
            __builtin_amdgcn_s_setprio(0);
        }
    };

    STAGE(0, 0);                       // 8 in flight
    int buf = 0;
    for (int k0 = 64; k0 < DIM; k0 += 64) {
        STAGE(buf ^ 1, k0);            // +8 -> 16 in flight
        WAITVM(8);                     // oldest 8 (current tile) landed
        __builtin_amdgcn_sched_barrier(0);
        __builtin_amdgcn_s_barrier();  // all waves' current tile visible
        CFENCE();
        COMPUTE(buf);                  // prefetch stays in flight underneath
        CFENCE();
        __builtin_amdgcn_s_barrier();  // all reads done before next overwrite
        buf ^= 1;
    }
    WAITVM(0);                         // drain last tile
    __builtin_amdgcn_sched_barrier(0);
    __builtin_amdgcn_s_barrier();
    CFENCE();
    COMPUTE(buf);

    // epilogue: val = silu(h) + t (t from bf16 A); bf16 store; row ss -> atomic
    #pragma unroll
    for (int i = 0; i < 4; i++) {
        int r0 = blk_m + wm + i * 16 + fq * 4;
        float ssp[4] = {0.f, 0.f, 0.f, 0.f};
        #pragma unroll
        for (int j = 0; j < 4; j++) {
            int col = blk_n + wn + j * 16 + fr;
            float bv = bias[col];
            #pragma unroll
            for (int r2 = 0; r2 < 4; r2++) {
                int gr = r0 + r2;
                float h = acc[i][j][r2] + bv;
                float t = bf2f(A[(size_t)gr * DIM + col]);
                float v = h / (1.f + __expf(-h)) + t;
                ssp[r2] += v * v;
                val[(size_t)gr * DIM + col] = f2bf(v);
            }
        }
        #pragma unroll
        for (int r2 = 0; r2 < 4; r2++) {
            float s = ssp[r2];
            s += __shfl_xor(s, 1); s += __shfl_xor(s, 2);
            s += __shfl_xor(s, 4); s += __shfl_xor(s, 8);
            if (fr == 0) atomicAdd(&ss[r0 + r2], s);
        }
    }
}

// ---------- x normalize: emb = val / max(||val||, eps); fp32 + bf16 out ----------
__global__ void norm_x_kernel(const u16* __restrict__ val, const float* __restrict__ ss,
                              float* __restrict__ emb, u16* __restrict__ emb_bf) {
    int row = blockIdx.x;
    float sc = 1.f / fmaxf(sqrtf(ss[row]), 1e-12f);
    size_t b = (size_t)row * DIM + threadIdx.x * 4;
    ushort4 v = *(const ushort4*)(val + b);
    float4 o;
    o.x = bf2f(v.x) * sc; o.y = bf2f(v.y) * sc;
    o.z = bf2f(v.z) * sc; o.w = bf2f(v.w) * sc;
    *(float4*)(emb + b) = o;
    ushort4 ob; ob.x = f2bf(o.x); ob.y = f2bf(o.y); ob.z = f2bf(o.z); ob.w = f2bf(o.w);
    *(ushort4*)(emb_bf + b) = ob;
}

// ---------- prototypes: one class per block; prebuilt queue, ushort4 gather ----------
__global__ __launch_bounds__(256)
void proto_kernel(const u16* __restrict__ val_bf, const float* __restrict__ ss,
                  const int* __restrict__ qcnt, const int* __restrict__ qlist,
                  u16* __restrict__ proto_bf) {
    __shared__ float red[4];
    const int cls = blockIdx.x, tid = threadIdx.x;
    int n = qcnt[cls]; if (n > 256) n = 256;
    const int* ql = qlist + (size_t)cls * 256;
    const bool act = tid < 192;                     // 192 * ushort4 = 768
    const size_t tb = (size_t)tid * 4;
    float a0 = 0.f, a1 = 0.f, a2 = 0.f, a3 = 0.f;
    int e = 0;
    for (; e + 2 <= n; e += 2) {
        int r0 = ql[e], r1 = ql[e + 1];
        float s0 = 1.f / fmaxf(sqrtf(ss[r0]), 1e-12f);
        float s1 = 1.f / fmaxf(sqrtf(ss[r1]), 1e-12f);
        if (act) {
            ushort4 u0 = *(const ushort4*)(val_bf + (size_t)r0 * DIM + tb);
            ushort4 u1 = *(const ushort4*)(val_bf + (size_t)r1 * DIM + tb);
            a0 += bf2f(u0.x) * s0 + bf2f(u1.x) * s1;
            a1 += bf2f(u0.y) * s0 + bf2f(u1.y) * s1;
            a2 += bf2f(u0.z) * s0 + bf2f(u1.z) * s1;
            a3 += bf2f(u0.w) * s0 + bf2f(u1.w) * s1;
        }
    }
    if (e < n) {
        int r0 = ql[e];
        float s0 = 1.f / fmaxf(sqrtf(ss[r0]), 1e-12f);
        if (act) {
            ushort4 u0 = *(const ushort4*)(val_bf + (size_t)r0 * DIM + tb);
            a0 += bf2f(u0.x) * s0; a1 += bf2f(u0.y) * s0;
            a2 += bf2f(u0.z) * s0; a3 += bf2f(u0.w) * s0;
        }
    }
    float inv_cnt = 1.f / fmaxf((float)n, 1.f);
    float m0 = a0 * inv_cnt, m1 = a1 * inv_cnt;
    float m2 = a2 * inv_cnt, m3 = a3 * inv_cnt;
    float tot = block_sum(m0 * m0 + m1 * m1 + m2 * m2 + m3 * m3, red);
    float sc2 = (n > 0) ? 1.f / fmaxf(sqrtf(tot), 1e-12f) : 0.f;
    if (act) {
        ushort4 o;
        o.x = f2bf(m0 * sc2); o.y = f2bf(m1 * sc2);
        o.z = f2bf(m2 * sc2); o.w = f2bf(m3 * sc2);
        *(ushort4*)(proto_bf + (size_t)cls * DIM + tb) = o;
    }
}

// ---------- cos GEMM (bf16 x bf16, glds both, swizzled, counted vmcnt) ----------
// grid = (CPAD/128, B_ROWS/128); fused exp -> logits
__global__ __launch_bounds__(256, 2)
void cos_gemm_kernel(const u16* __restrict__ Ab, const u16* __restrict__ Pb,
                     float* __restrict__ logits) {
    __shared__ u16 As[2][128 * 64];
    __shared__ u16 Bs[2][128 * 64];
    const int tid  = threadIdx.x;
    const int wave = tid >> 6, lane = tid & 63;
    const int fq = lane >> 4, fr = lane & 15;

    const int swz = xcd_swizzle();
    const int blk_m = (swz / gridDim.x) * 128;
    const int blk_n = (swz % gridDim.x) * 128;

    const int wm = (wave & 1) * 64, wn = (wave >> 1) * 64;

    v4f acc[4][4];
    #pragma unroll
    for (int i = 0; i < 4; i++)
        #pragma unroll
        for (int j = 0; j < 4; j++) acc[i][j] = (v4f){0.f, 0.f, 0.f, 0.f};

    const int rb  = lane >> 3;
    const int cbs = ((lane & 7) ^ rb) * 8;
    const u16* gA = Ab + (size_t)(blk_m + wave * 8 + rb) * DIM + cbs;
    const u16* gB = Pb + (size_t)(blk_n + wave * 8 + rb) * DIM + cbs;

    auto STAGE = [&](int buf, int k0) {
        #pragma unroll
        for (int p = 0; p < 4; p++) {
            glds16(gA + (size_t)p * 32 * DIM + k0, &As[buf][p * 2048 + wave * 512]);
            glds16(gB + (size_t)p * 32 * DIM + k0, &Bs[buf][p * 2048 + wave * 512]);
        }
    };
    auto COMPUTE = [&](int buf) {
        #pragma unroll
        for (int ks = 0; ks < 2; ks++) {
            const int gbase = ks * 4;
            v8bf af[4], bfr[4];
            #pragma unroll
            for (int i = 0; i < 4; i++) {
                int rowa = wm + i * 16 + fr;
                int rowb = wn + i * 16 + fr;
                int g    = (gbase + fq) ^ (fr & 7);
                af[i]  = *(const v8bf*)(&As[buf][rowa * 64 + g * 8]);
                bfr[i] = *(const v8bf*)(&Bs[buf][rowb * 64 + g * 8]);
            }
            __builtin_amdgcn_s_setprio(1);
            #pragma unroll
            for (int i = 0; i < 4; i++)
                #pragma unroll
                for (int j = 0; j < 4; j++)
                    acc[i][j] = __builtin_amdgcn_mfma_f32_16x16x32_bf16(
                        af[i], bfr[j], acc[i][j], 0, 0, 0);
            __builtin_amdgcn_s_setprio(0);
        }
    };

    STAGE(0, 0);
    int buf = 0;
    for (int k0 = 64; k0 < DIM; k0 += 64) {
        STAGE(buf ^ 1, k0);
        WAITVM(8);
        __builtin_amdgcn_sched_barrier(0);
        __builtin_amdgcn_s_barrier();
        CFENCE();
        COMPUTE(buf);
        CFENCE();
        __builtin_amdgcn_s_barrier();
        buf ^= 1;
    }
    WAITVM(0);
    __builtin_amdgcn_sched_barrier(0);
    __builtin_amdgcn_s_barrier();
    CFENCE();
    COMPUTE(buf);

    #pragma unroll
    for (int i = 0; i < 4; i++) {
        int r0 = blk_m + wm + i * 16 + fq * 4;
        #pragma unroll
        for (int j = 0; j < 4; j++) {
            int col = blk_n + wn + j * 16 + fr;
            if (col < N_CLS) {
                #pragma unroll
                for (int r2 = 0; r2 < 4; r2++) {
                    float c = acc[i][j][r2];
                    logits[(size_t)(r0 + r2) * N_CLS + col] =
                        __expf(32.0f * (c - 1.0f)) * (1.0f / 0.11f);
                }
            }
        }
    }
}

// ---------- softmax over logits rows ----------
__global__ __launch_bounds__(256)
void softmax_kernel(const float* __restrict__ logits, float* __restrict__ predicts) {
    __shared__ float redm[4];
    __shared__ float reds[4];
    int row = blockIdx.x, tid = threadIdx.x;
    const float* lr = logits + (size_t)row * N_CLS;
    float4 lg = make_float4(-1.f, -1.f, -1.f, -1.f);
    bool act = tid < N_CLS / 4;   // 250
    if (act) lg = *(const float4*)(lr + tid * 4);
    float mx = fmaxf(fmaxf(lg.x, lg.y), fmaxf(lg.z, lg.w));  // logits >= 0
    float mxt = block_max(mx, redm);
    float4 e = make_float4(0.f, 0.f, 0.f, 0.f);
    float s = 0.f;
    if (act) {
        e.x = __expf(lg.x - mxt); e.y = __expf(lg.y - mxt);
        e.z = __expf(lg.z - mxt); e.w = __expf(lg.w - mxt);
        s = e.x + e.y + e.z + e.w;
    }
    float st = block_sum(s, reds);
    float inv = 1.f / st;
    if (act) {
        float4 o; o.x = e.x * inv; o.y = e.y * inv; o.z = e.z * inv; o.w = e.w * inv;
        *(float4*)(predicts + (size_t)row * N_CLS + tid * 4) = o;
    }
}

// ---------- launch ----------
extern "C" void kernel_launch(void* const* d_in, const int* in_sizes, int n_in,
                              void* d_out, int out_size, void* d_ws, size_t ws_size,
                              hipStream_t stream) {
    const float* x      = (const float*)d_in[0];
    const float* sup    = (const float*)d_in[1];
    const int*   labels = (const int*)d_in[2];
    const float* W      = (const float*)d_in[3];
    const float* bias   = (const float*)d_in[4];

    float* predicts = (float*)d_out;
    float* logits   = predicts + (size_t)B_ROWS * N_CLS;
    float* emb      = logits + (size_t)B_ROWS * N_CLS;   // 8192x768 fp32

    char* ws = (char*)d_ws;
    size_t off = 0;
    u16*   w_bf     = (u16*)(ws + off);   off += (size_t)DIM * DIM * 2;
    u16*   x_bf     = (u16*)(ws + off);   off += (size_t)B_ROWS * DIM * 2;
    u16*   sup_bf   = (u16*)(ws + off);   off += (size_t)MSUP_PAD * DIM * 2;
    u16*   val_x    = (u16*)(ws + off);   off += (size_t)B_ROWS * DIM * 2;
    u16*   val_sup  = (u16*)(ws + off);   off += (size_t)MSUP_PAD * DIM * 2;
    u16*   emb_bf   = (u16*)(ws + off);   off += (size_t)B_ROWS * DIM * 2;
    u16*   proto_bf = (u16*)(ws + off);   off += (size_t)CPAD * DIM * 2;
    float* ss_sup   = (float*)(ws + off); off += (size_t)MSUP_PAD * 4;
    float* ss_x     = (float*)(ws + off); off += (size_t)B_ROWS * 4;
    int*   qcnt     = (int*)(ws + off);   off += (size_t)CPAD * 4;
    int*   qlist    = (int*)(ws + off);   off += (size_t)N_CLS * 256 * 4;

    // zero ss_sup, ss_x, qcnt in one shot (contiguous)
    hipMemsetAsync(ss_sup, 0, ((size_t)MSUP_PAD + B_ROWS + CPAD) * 4, stream);

    // bf16 conversions + per-class queues
    conv_pad_kernel<<<DIM / 4,      256, 0, stream>>>(W,   w_bf,   DIM);
    conv_pad_kernel<<<B_ROWS / 4,   256, 0, stream>>>(x,   x_bf,   B_ROWS);
    conv_pad_kernel<<<MSUP_PAD / 4, 256, 0, stream>>>(sup, sup_bf, N_SUP);
    build_queues_kernel<<<(N_SUP + 255) / 256, 256, 0, stream>>>(labels, qcnt, qlist);

    // adapter GEMMs (val = silu(A@W^T+b)+A, bf16; per-row ss)
    adapter_gemm_kernel<<<dim3(DIM / 128, B_ROWS / 128), 256, 0, stream>>>(
        x_bf, w_bf, bias, val_x, ss_x);
    adapter_gemm_kernel<<<dim3(DIM / 128, MSUP_PAD / 128), 256, 0, stream>>>(
        sup_bf, w_bf, bias, val_sup, ss_sup);

    // x normalize -> emb (fp32, d_out) + emb_bf
    norm_x_kernel<<<B_ROWS, 192, 0, stream>>>(val_x, ss_x, emb, emb_bf);

    // prototypes (classes >= N_CLS: qcnt==0 -> zeros)
    proto_kernel<<<CPAD, 256, 0, stream>>>(val_sup, ss_sup, qcnt, qlist, proto_bf);

    // cos + exp -> logits (d_out), then softmax -> predicts (d_out)
    cos_gemm_kernel<<<dim3(CPAD / 128, B_ROWS / 128), 256, 0, stream>>>(
        emb_bf, proto_bf, logits);
    softmax_kernel<<<B_ROWS, 256, 0, stream>>>(logits, predicts);
}